// Round 1
// baseline (1824.554 us; speedup 1.0000x reference)
//
#include <hip/hip_runtime.h>
#include <cmath>

// Problem constants (from reference)
constexpr int N  = 50000;
constexpr int E  = 800000;
constexpr int D  = 128;
constexpr int H  = 4;
constexpr int DH = 32;
constexpr int L  = 2;
constexpr float ALPHA = 0.3f;

constexpr int SCAN_B = 256;
constexpr int NB = (N + SCAN_B - 1) / SCAN_B; // 196 blocks

// ---------------- CSR build ----------------

__global__ void k_count(const int* __restrict__ edges, int* __restrict__ cnt) {
    int e = blockIdx.x * blockDim.x + threadIdx.x;
    if (e < E) atomicAdd(&cnt[edges[2 * e]], 1);
}

__global__ void k_scanA(const int* __restrict__ cnt, int* __restrict__ excl,
                        int* __restrict__ bsum) {
    __shared__ int sm[SCAN_B];
    int t = threadIdx.x;
    int i = blockIdx.x * SCAN_B + t;
    int v = (i < N) ? cnt[i] : 0;
    sm[t] = v;
    __syncthreads();
    for (int off = 1; off < SCAN_B; off <<= 1) {
        int add = (t >= off) ? sm[t - off] : 0;
        __syncthreads();
        sm[t] += add;
        __syncthreads();
    }
    if (i < N) excl[i] = sm[t] - v;           // exclusive within block
    if (t == SCAN_B - 1) bsum[blockIdx.x] = sm[t];
}

__global__ void k_scanB(int* __restrict__ bsum) {
    __shared__ int sm[SCAN_B];
    int t = threadIdx.x;
    int v = (t < NB) ? bsum[t] : 0;
    sm[t] = v;
    __syncthreads();
    for (int off = 1; off < SCAN_B; off <<= 1) {
        int add = (t >= off) ? sm[t - off] : 0;
        __syncthreads();
        sm[t] += add;
        __syncthreads();
    }
    if (t < NB) bsum[t] = sm[t] - v;          // exclusive across blocks
}

__global__ void k_scanC(int* __restrict__ rowptr, const int* __restrict__ bsum,
                        int* __restrict__ head) {
    int i = blockIdx.x * SCAN_B + threadIdx.x;
    if (i < N) {
        int r = rowptr[i] + bsum[blockIdx.x];
        rowptr[i] = r;
        head[i]   = r;
    }
    if (i == 0) rowptr[N] = E;
}

__global__ void k_scatter(const int* __restrict__ edges, const float* __restrict__ evals,
                          int* __restrict__ head, int* __restrict__ sdst,
                          float* __restrict__ sval) {
    int e = blockIdx.x * blockDim.x + threadIdx.x;
    if (e < E) {
        int2 sd = ((const int2*)edges)[e];
        int pos = atomicAdd(&head[sd.x], 1);
        sdst[pos] = sd.y;
        sval[pos] = evals[e];
    }
}

// ---------------- Stage 1: x = seg_softmax(edge_vals) weighted gather of emb[dst] ----
// One wave (64 lanes) per node; lane owns 2 feature dims (float2).
__global__ __launch_bounds__(256) void k_agg0(const int* __restrict__ rowptr,
                                              const int* __restrict__ sdst,
                                              const float* __restrict__ sval,
                                              const float* __restrict__ emb,
                                              float* __restrict__ x0) {
    int t = threadIdx.x, w = t >> 6, lane = t & 63;
    int node = blockIdx.x * 4 + w;
    if (node >= N) return;
    int b = rowptr[node], e = rowptr[node + 1];
    const float2* emb2 = (const float2*)emb;
    float2 acc = {0.f, 0.f};
    float ssum = 0.f;
    for (int j = b; j < e; ++j) {
        int dn = sdst[j];
        float wgt = __expf(sval[j]);     // max-shift cancels in softmax
        ssum += wgt;
        float2 v = emb2[(size_t)dn * 64 + lane];
        acc.x += wgt * v.x;
        acc.y += wgt * v.y;
    }
    float inv = (e > b) ? 1.f / ssum : 0.f;
    float2 r = {acc.x * inv, acc.y * inv};
    ((float2*)x0)[(size_t)node * 64 + lane] = r;
}

// ---------------- Per-layer: per-node aS/aN ----------------
// Block = 256 thr = 4 waves = 4 nodes. K (16KB) + attn (1KB) staged in LDS.
__global__ __launch_bounds__(256) void k_prep(const float* __restrict__ x,
                                              const float* __restrict__ kern,  // H*DH*DH of this layer
                                              const float* __restrict__ attn,  // H*2*DH of this layer
                                              float* __restrict__ aSN) {
    __shared__ float Ks[H * DH * DH];   // 4096 f32
    __shared__ float As[H * 2 * DH];    // 256 f32
    __shared__ float xs[4][D];
    int t = threadIdx.x;
#pragma unroll
    for (int i = 0; i < 16; ++i) Ks[t + i * 256] = kern[t + i * 256];
    As[t] = attn[t];
    int w = t >> 6, lane = t & 63;
    int node = blockIdx.x * 4 + w;
    if (node < N) {
        float2 xv = ((const float2*)x)[(size_t)node * 64 + lane];
        xs[w][2 * lane]     = fmaxf(xv.x, 0.f);   // relu(x)
        xs[w][2 * lane + 1] = fmaxf(xv.y, 0.f);
    }
    __syncthreads();
    if (node >= N) return;
    int f = lane & 31;
#pragma unroll
    for (int hh = 0; hh < 2; ++hh) {
        int h = (lane >> 5) + 2 * hh;
        float y = 0.f;
#pragma unroll
        for (int d = 0; d < DH; ++d)
            y += xs[w][h * DH + d] * Ks[(h * DH + d) * DH + f];
        y = fmaxf(y, 0.f);                       // relu(einsum)
        float aS = y * As[h * 2 * DH + f];        // attn first half  (self/src)
        float aN = y * As[h * 2 * DH + DH + f];   // attn second half (neigh/dst)
#pragma unroll
        for (int m = 1; m < 32; m <<= 1) {
            aS += __shfl_xor(aS, m);
            aN += __shfl_xor(aN, m);
        }
        if (f == 0) {
            aSN[(size_t)node * 8 + h]     = aS;
            aSN[(size_t)node * 8 + 4 + h] = aN;
        }
    }
}

// ---------------- Per-layer: global softmax denominator S[h] ----------------
// One wave per node; 16 edges x 4 heads in parallel per iteration.
__global__ __launch_bounds__(256) void k_edge(const int* __restrict__ rowptr,
                                              const int* __restrict__ sdst,
                                              const float* __restrict__ aSN,
                                              float* __restrict__ S) {
    int t = threadIdx.x, w = t >> 6, lane = t & 63;
    int node = blockIdx.x * 4 + w;
    if (node >= N) return;
    int b = rowptr[node], e = rowptr[node + 1];
    int h = lane & 3;
    float aS = aSN[(size_t)node * 8 + h];
    float local = 0.f;
    for (int j0 = b; j0 < e; j0 += 16) {
        int j = j0 + (lane >> 2);
        if (j < e) {
            int dn = sdst[j];
            float a = aS + aSN[(size_t)dn * 8 + 4 + h];
            a = (a >= 0.f) ? a : ALPHA * a;      // leaky_relu
            local += __expf(a);                  // global softmax, max-shift cancels
        }
    }
#pragma unroll
    for (int m = 4; m < 64; m <<= 1) local += __shfl_xor(local, m);
    if (lane < 4) atomicAdd(&S[lane], local);
}

// ---------------- Per-layer: fused seg-softmax(p) + aggregation + tanh ------------
__global__ __launch_bounds__(256) void k_agg(const int* __restrict__ rowptr,
                                             const int* __restrict__ sdst,
                                             const float* __restrict__ aSN,
                                             const float* __restrict__ S,
                                             const float* __restrict__ xin,
                                             float* __restrict__ xout,
                                             float* __restrict__ out, int l) {
    int t = threadIdx.x, w = t >> 6, lane = t & 63;
    int node = blockIdx.x * 4 + w;
    if (node >= N) return;
    int b = rowptr[node], e = rowptr[node + 1];
    int h4 = lane & 3;
    float aS   = aSN[(size_t)node * 8 + h4];
    float invS = 1.f / S[h4];
    const float2* x2 = (const float2*)xin;
    float2 acc = {0.f, 0.f};
    float ssum = 0.f;
    for (int j = b; j < e; ++j) {
        int dn = sdst[j];
        // recompute attention weight (bit-identical to k_edge)
        float a = aS + aSN[(size_t)dn * 8 + 4 + h4];
        a = (a >= 0.f) ? a : ALPHA * a;
        float p = __expf(a) * invS;              // global softmax output
        float wgt = __expf(p);                   // seg softmax numerator (max-shift cancels)
        ssum += wgt;                             // identical across lanes sharing lane&3
        float wb = __shfl(wgt, lane >> 4);       // broadcast head (lane>>4)'s weight
        float2 v = x2[(size_t)dn * 64 + lane];
        v.x = fmaxf(v.x, 0.f);                   // neigh = relu(x)[dst]
        v.y = fmaxf(v.y, 0.f);
        acc.x += wb * v.x;
        acc.y += wb * v.y;
    }
    float ssb = __shfl(ssum, lane >> 4);
    float inv = (e > b) ? 1.f / ssb : 0.f;
    float2 r;
    r.x = tanhf(acc.x * inv);
    r.y = tanhf(acc.y * inv);
    ((float2*)xout)[(size_t)node * 64 + lane] = r;
    // out[node, l*128 + 2*lane .. +1], row stride L*D=256 f32 = 128 float2
    ((float2*)out)[(size_t)node * 128 + l * 64 + lane] = r;
}

// ---------------- launch ----------------
extern "C" void kernel_launch(void* const* d_in, const int* in_sizes, int n_in,
                              void* d_out, int out_size, void* d_ws, size_t ws_size,
                              hipStream_t stream) {
    (void)in_sizes; (void)n_in; (void)out_size; (void)ws_size;
    const float* emb   = (const float*)d_in[0];  // N*D
    const float* evals = (const float*)d_in[1];  // E
    const float* kern  = (const float*)d_in[2];  // L*H*DH*DH
    const float* attn  = (const float*)d_in[3];  // L*H*2*DH
    const int*   edges = (const int*)d_in[4];    // E*2
    float* out = (float*)d_out;

    char* ws = (char*)d_ws;
    size_t off = 0;
    auto take = [&](size_t bytes) -> void* {
        void* p = ws + off;
        off = (off + bytes + 255) & ~(size_t)255;
        return p;
    };
    int*   cnt    = (int*)take((size_t)N * 4);
    int*   rowptr = (int*)take((size_t)(N + 1) * 4);
    int*   head   = (int*)take((size_t)N * 4);
    int*   bsum   = (int*)take((size_t)NB * 4);
    int*   sdst   = (int*)take((size_t)E * 4);
    float* sval   = (float*)take((size_t)E * 4);
    float* aSN    = (float*)take((size_t)N * 8 * 4);
    float* S      = (float*)take(64);            // 2 layers x 4 heads
    float* x0     = (float*)take((size_t)N * D * 4);
    float* x1     = (float*)take((size_t)N * D * 4);

    hipMemsetAsync(cnt, 0, (size_t)N * 4, stream);
    hipMemsetAsync(S, 0, 64, stream);

    int eb = (E + 255) / 256;
    k_count<<<eb, 256, 0, stream>>>(edges, cnt);
    k_scanA<<<NB, SCAN_B, 0, stream>>>(cnt, rowptr, bsum);
    k_scanB<<<1, SCAN_B, 0, stream>>>(bsum);
    k_scanC<<<NB, SCAN_B, 0, stream>>>(rowptr, bsum, head);
    k_scatter<<<eb, 256, 0, stream>>>(edges, evals, head, sdst, sval);

    int nb = (N + 3) / 4;   // 4 nodes (waves) per block
    k_agg0<<<nb, 256, 0, stream>>>(rowptr, sdst, sval, emb, x0);

    float* xin = x0;
    float* xout = x1;
    for (int l = 0; l < L; ++l) {
        k_prep<<<nb, 256, 0, stream>>>(xin, kern + (size_t)l * H * DH * DH,
                                       attn + (size_t)l * H * 2 * DH, aSN);
        k_edge<<<nb, 256, 0, stream>>>(rowptr, sdst, aSN, S + l * 4);
        k_agg<<<nb, 256, 0, stream>>>(rowptr, sdst, aSN, S + l * 4, xin, xout, out, l);
        float* tmp = xin; xin = xout; xout = tmp;
    }
}

// Round 2
// 576.029 us; speedup vs baseline: 3.1675x; 3.1675x over previous
//
#include <hip/hip_runtime.h>
#include <cmath>

// Problem constants (from reference)
constexpr int N  = 50000;
constexpr int E  = 800000;
constexpr int D  = 128;
constexpr int H  = 4;
constexpr int DH = 32;
constexpr int L  = 2;
constexpr float ALPHA = 0.3f;

constexpr int SCAN_B = 256;
constexpr int NB = (N + SCAN_B - 1) / SCAN_B; // 196 blocks
constexpr int EDGE_BLOCKS = 512;              // k_edge reduction grid

// ---------------- CSR build ----------------

__global__ void k_count(const int* __restrict__ edges, int* __restrict__ cnt) {
    int e = blockIdx.x * blockDim.x + threadIdx.x;
    if (e < E) atomicAdd(&cnt[edges[2 * e]], 1);
}

__global__ void k_scanA(const int* __restrict__ cnt, int* __restrict__ excl,
                        int* __restrict__ bsum) {
    __shared__ int sm[SCAN_B];
    int t = threadIdx.x;
    int i = blockIdx.x * SCAN_B + t;
    int v = (i < N) ? cnt[i] : 0;
    sm[t] = v;
    __syncthreads();
    for (int off = 1; off < SCAN_B; off <<= 1) {
        int add = (t >= off) ? sm[t - off] : 0;
        __syncthreads();
        sm[t] += add;
        __syncthreads();
    }
    if (i < N) excl[i] = sm[t] - v;           // exclusive within block
    if (t == SCAN_B - 1) bsum[blockIdx.x] = sm[t];
}

__global__ void k_scanB(int* __restrict__ bsum) {
    __shared__ int sm[SCAN_B];
    int t = threadIdx.x;
    int v = (t < NB) ? bsum[t] : 0;
    sm[t] = v;
    __syncthreads();
    for (int off = 1; off < SCAN_B; off <<= 1) {
        int add = (t >= off) ? sm[t - off] : 0;
        __syncthreads();
        sm[t] += add;
        __syncthreads();
    }
    if (t < NB) bsum[t] = sm[t] - v;          // exclusive across blocks
}

__global__ void k_scanC(int* __restrict__ rowptr, const int* __restrict__ bsum,
                        int* __restrict__ head) {
    int i = blockIdx.x * SCAN_B + threadIdx.x;
    if (i < N) {
        int r = rowptr[i] + bsum[blockIdx.x];
        rowptr[i] = r;
        head[i]   = r;
    }
    if (i == 0) rowptr[N] = E;
}

__global__ void k_scatter(const int* __restrict__ edges, const float* __restrict__ evals,
                          int* __restrict__ head, int* __restrict__ sdst,
                          float* __restrict__ sval) {
    int e = blockIdx.x * blockDim.x + threadIdx.x;
    if (e < E) {
        int2 sd = ((const int2*)edges)[e];
        int pos = atomicAdd(&head[sd.x], 1);
        sdst[pos] = sd.y;
        sval[pos] = evals[e];
    }
}

// ---------------- Stage 1: x = seg_softmax(edge_vals) weighted gather of emb[dst] ----
// One wave (64 lanes) per node; lane owns 2 feature dims (float2).
__global__ __launch_bounds__(256) void k_agg0(const int* __restrict__ rowptr,
                                              const int* __restrict__ sdst,
                                              const float* __restrict__ sval,
                                              const float* __restrict__ emb,
                                              float* __restrict__ x0) {
    int t = threadIdx.x, w = t >> 6, lane = t & 63;
    int node = blockIdx.x * 4 + w;
    if (node >= N) return;
    int b = rowptr[node], e = rowptr[node + 1];
    const float2* emb2 = (const float2*)emb;
    float2 acc = {0.f, 0.f};
    float ssum = 0.f;
    for (int j = b; j < e; ++j) {
        int dn = sdst[j];
        float wgt = __expf(sval[j]);     // max-shift cancels in softmax
        ssum += wgt;
        float2 v = emb2[(size_t)dn * 64 + lane];
        acc.x += wgt * v.x;
        acc.y += wgt * v.y;
    }
    float inv = (e > b) ? 1.f / ssum : 0.f;
    float2 r = {acc.x * inv, acc.y * inv};
    ((float2*)x0)[(size_t)node * 64 + lane] = r;
}

// ---------------- Per-layer: per-node aS/aN ----------------
// Block = 256 thr = 4 waves = 4 nodes. K (16KB) + attn (1KB) staged in LDS.
__global__ __launch_bounds__(256) void k_prep(const float* __restrict__ x,
                                              const float* __restrict__ kern,  // H*DH*DH of this layer
                                              const float* __restrict__ attn,  // H*2*DH of this layer
                                              float* __restrict__ aSN) {
    __shared__ float Ks[H * DH * DH];   // 4096 f32
    __shared__ float As[H * 2 * DH];    // 256 f32
    __shared__ float xs[4][D];
    int t = threadIdx.x;
#pragma unroll
    for (int i = 0; i < 16; ++i) Ks[t + i * 256] = kern[t + i * 256];
    As[t] = attn[t];
    int w = t >> 6, lane = t & 63;
    int node = blockIdx.x * 4 + w;
    if (node < N) {
        float2 xv = ((const float2*)x)[(size_t)node * 64 + lane];
        xs[w][2 * lane]     = fmaxf(xv.x, 0.f);   // relu(x)
        xs[w][2 * lane + 1] = fmaxf(xv.y, 0.f);
    }
    __syncthreads();
    if (node >= N) return;
    int f = lane & 31;
#pragma unroll
    for (int hh = 0; hh < 2; ++hh) {
        int h = (lane >> 5) + 2 * hh;
        float y = 0.f;
#pragma unroll
        for (int d = 0; d < DH; ++d)
            y += xs[w][h * DH + d] * Ks[(h * DH + d) * DH + f];
        y = fmaxf(y, 0.f);                       // relu(einsum)
        float aS = y * As[h * 2 * DH + f];        // attn first half  (self/src)
        float aN = y * As[h * 2 * DH + DH + f];   // attn second half (neigh/dst)
#pragma unroll
        for (int m = 1; m < 32; m <<= 1) {
            aS += __shfl_xor(aS, m);
            aN += __shfl_xor(aN, m);
        }
        if (f == 0) {
            aSN[(size_t)node * 8 + h]     = aS;
            aSN[(size_t)node * 8 + 4 + h] = aN;
        }
    }
}

// ---------------- Per-layer: global softmax denominator S[h] ----------------
// Edge-parallel grid-stride; hierarchical reduction; ONE atomicAdd/head/block.
__global__ __launch_bounds__(256) void k_edge(const int* __restrict__ edges,
                                              const float* __restrict__ aSN,
                                              float* __restrict__ S) {
    float local[H] = {0.f, 0.f, 0.f, 0.f};
    int stride = gridDim.x * blockDim.x;
    const int2* e2 = (const int2*)edges;
    const float4* a4 = (const float4*)aSN;
    for (int e = blockIdx.x * blockDim.x + threadIdx.x; e < E; e += stride) {
        int2 sd = e2[e];
        float4 vS = a4[(size_t)sd.x * 2];        // aS[src, 0..3]
        float4 vN = a4[(size_t)sd.y * 2 + 1];    // aN[dst, 0..3]
        float a0 = vS.x + vN.x, a1 = vS.y + vN.y, a2 = vS.z + vN.z, a3 = vS.w + vN.w;
        a0 = (a0 >= 0.f) ? a0 : ALPHA * a0;
        a1 = (a1 >= 0.f) ? a1 : ALPHA * a1;
        a2 = (a2 >= 0.f) ? a2 : ALPHA * a2;
        a3 = (a3 >= 0.f) ? a3 : ALPHA * a3;
        local[0] += __expf(a0);
        local[1] += __expf(a1);
        local[2] += __expf(a2);
        local[3] += __expf(a3);
    }
#pragma unroll
    for (int h = 0; h < H; ++h)
#pragma unroll
        for (int m = 1; m < 64; m <<= 1) local[h] += __shfl_xor(local[h], m);
    __shared__ float sm[4][H];
    int lane = threadIdx.x & 63, w = threadIdx.x >> 6;
    if (lane == 0)
#pragma unroll
        for (int h = 0; h < H; ++h) sm[w][h] = local[h];
    __syncthreads();
    if (threadIdx.x < H) {
        float s = sm[0][threadIdx.x] + sm[1][threadIdx.x] +
                  sm[2][threadIdx.x] + sm[3][threadIdx.x];
        atomicAdd(&S[threadIdx.x], s);
    }
}

// ---------------- Per-layer: fused seg-softmax(p) + aggregation + tanh ------------
__global__ __launch_bounds__(256) void k_agg(const int* __restrict__ rowptr,
                                             const int* __restrict__ sdst,
                                             const float* __restrict__ aSN,
                                             const float* __restrict__ S,
                                             const float* __restrict__ xin,
                                             float* __restrict__ xout,
                                             float* __restrict__ out, int l) {
    int t = threadIdx.x, w = t >> 6, lane = t & 63;
    int node = blockIdx.x * 4 + w;
    if (node >= N) return;
    int b = rowptr[node], e = rowptr[node + 1];
    int h4 = lane & 3;
    float aS   = aSN[(size_t)node * 8 + h4];
    float invS = 1.f / S[h4];
    const float2* x2 = (const float2*)xin;
    float2 acc = {0.f, 0.f};
    float ssum = 0.f;
    for (int j = b; j < e; ++j) {
        int dn = sdst[j];
        float a = aS + aSN[(size_t)dn * 8 + 4 + h4];
        a = (a >= 0.f) ? a : ALPHA * a;
        float p = __expf(a) * invS;              // global softmax output
        float wgt = __expf(p);                   // seg softmax numerator (max-shift cancels)
        ssum += wgt;                             // identical across lanes sharing lane&3
        float wb = __shfl(wgt, lane >> 4);       // broadcast head (lane>>4)'s weight
        float2 v = x2[(size_t)dn * 64 + lane];
        v.x = fmaxf(v.x, 0.f);                   // neigh = relu(x)[dst]
        v.y = fmaxf(v.y, 0.f);
        acc.x += wb * v.x;
        acc.y += wb * v.y;
    }
    float ssb = __shfl(ssum, lane >> 4);
    float inv = (e > b) ? 1.f / ssb : 0.f;
    float2 r;
    r.x = tanhf(acc.x * inv);
    r.y = tanhf(acc.y * inv);
    ((float2*)xout)[(size_t)node * 64 + lane] = r;
    // out[node, l*128 + 2*lane .. +1], row stride L*D=256 f32 = 128 float2
    ((float2*)out)[(size_t)node * 128 + l * 64 + lane] = r;
}

// ---------------- launch ----------------
extern "C" void kernel_launch(void* const* d_in, const int* in_sizes, int n_in,
                              void* d_out, int out_size, void* d_ws, size_t ws_size,
                              hipStream_t stream) {
    (void)in_sizes; (void)n_in; (void)out_size; (void)ws_size;
    const float* emb   = (const float*)d_in[0];  // N*D
    const float* evals = (const float*)d_in[1];  // E
    const float* kern  = (const float*)d_in[2];  // L*H*DH*DH
    const float* attn  = (const float*)d_in[3];  // L*H*2*DH
    const int*   edges = (const int*)d_in[4];    // E*2
    float* out = (float*)d_out;

    char* ws = (char*)d_ws;
    size_t off = 0;
    auto take = [&](size_t bytes) -> void* {
        void* p = ws + off;
        off = (off + bytes + 255) & ~(size_t)255;
        return p;
    };
    int*   cnt    = (int*)take((size_t)N * 4);
    int*   rowptr = (int*)take((size_t)(N + 1) * 4);
    int*   head   = (int*)take((size_t)N * 4);
    int*   bsum   = (int*)take((size_t)NB * 4);
    int*   sdst   = (int*)take((size_t)E * 4);
    float* sval   = (float*)take((size_t)E * 4);
    float* aSN    = (float*)take((size_t)N * 8 * 4);
    float* S      = (float*)take(64);            // 2 layers x 4 heads
    float* x0     = (float*)take((size_t)N * D * 4);
    float* x1     = (float*)take((size_t)N * D * 4);

    hipMemsetAsync(cnt, 0, (size_t)N * 4, stream);
    hipMemsetAsync(S, 0, 64, stream);

    int eb = (E + 255) / 256;
    k_count<<<eb, 256, 0, stream>>>(edges, cnt);
    k_scanA<<<NB, SCAN_B, 0, stream>>>(cnt, rowptr, bsum);
    k_scanB<<<1, SCAN_B, 0, stream>>>(bsum);
    k_scanC<<<NB, SCAN_B, 0, stream>>>(rowptr, bsum, head);
    k_scatter<<<eb, 256, 0, stream>>>(edges, evals, head, sdst, sval);

    int nb = (N + 3) / 4;   // 4 nodes (waves) per block
    k_agg0<<<nb, 256, 0, stream>>>(rowptr, sdst, sval, emb, x0);

    float* xin = x0;
    float* xout = x1;
    for (int l = 0; l < L; ++l) {
        k_prep<<<nb, 256, 0, stream>>>(xin, kern + (size_t)l * H * DH * DH,
                                       attn + (size_t)l * H * 2 * DH, aSN);
        k_edge<<<EDGE_BLOCKS, 256, 0, stream>>>(edges, aSN, S + l * 4);
        k_agg<<<nb, 256, 0, stream>>>(rowptr, sdst, aSN, S + l * 4, xin, xout, out, l);
        float* tmp = xin; xin = xout; xout = tmp;
    }
}

// Round 3
// 418.058 us; speedup vs baseline: 4.3644x; 1.3779x over previous
//
#include <hip/hip_runtime.h>
#include <hip/hip_fp16.h>
#include <cmath>

// Problem constants (from reference)
constexpr int N  = 50000;
constexpr int E  = 800000;
constexpr int D  = 128;
constexpr int H  = 4;
constexpr int DH = 32;
constexpr int L  = 2;
constexpr float ALPHA = 0.3f;

constexpr int SCAN_B = 256;
constexpr int NB = (N + SCAN_B - 1) / SCAN_B; // 196 blocks
constexpr int EDGE_BLOCKS = 512;              // k_edge reduction grid

__device__ __forceinline__ float fast_tanh(float x) {
    // tanh(x) = 1 - 2/(exp(2x)+1); exact saturation at +/-inf, err ~1e-6
    return 1.f - 2.f / (__expf(2.f * x) + 1.f);
}

// ---------------- CSR build ----------------

__global__ void k_count(const int* __restrict__ edges, int* __restrict__ cnt) {
    int e = blockIdx.x * blockDim.x + threadIdx.x;
    if (e < E) atomicAdd(&cnt[edges[2 * e]], 1);
}

__global__ void k_scanA(const int* __restrict__ cnt, int* __restrict__ excl,
                        int* __restrict__ bsum) {
    __shared__ int sm[SCAN_B];
    int t = threadIdx.x;
    int i = blockIdx.x * SCAN_B + t;
    int v = (i < N) ? cnt[i] : 0;
    sm[t] = v;
    __syncthreads();
    for (int off = 1; off < SCAN_B; off <<= 1) {
        int add = (t >= off) ? sm[t - off] : 0;
        __syncthreads();
        sm[t] += add;
        __syncthreads();
    }
    if (i < N) excl[i] = sm[t] - v;           // exclusive within block
    if (t == SCAN_B - 1) bsum[blockIdx.x] = sm[t];
}

__global__ void k_scanB(int* __restrict__ bsum) {
    __shared__ int sm[SCAN_B];
    int t = threadIdx.x;
    int v = (t < NB) ? bsum[t] : 0;
    sm[t] = v;
    __syncthreads();
    for (int off = 1; off < SCAN_B; off <<= 1) {
        int add = (t >= off) ? sm[t - off] : 0;
        __syncthreads();
        sm[t] += add;
        __syncthreads();
    }
    if (t < NB) bsum[t] = sm[t] - v;          // exclusive across blocks
}

__global__ void k_scanC(int* __restrict__ rowptr, const int* __restrict__ bsum,
                        int* __restrict__ head) {
    int i = blockIdx.x * SCAN_B + threadIdx.x;
    if (i < N) {
        int r = rowptr[i] + bsum[blockIdx.x];
        rowptr[i] = r;
        head[i]   = r;
    }
    if (i == 0) rowptr[N] = E;
}

__global__ void k_scatter(const int* __restrict__ edges, const float* __restrict__ evals,
                          int* __restrict__ head, int* __restrict__ sdst,
                          float* __restrict__ sval) {
    int e = blockIdx.x * blockDim.x + threadIdx.x;
    if (e < E) {
        int2 sd = ((const int2*)edges)[e];
        int pos = atomicAdd(&head[sd.x], 1);
        sdst[pos] = sd.y;
        sval[pos] = evals[e];
    }
}

// ---------------- emb f32 -> fp16 ----------------
__global__ __launch_bounds__(256) void k_cvt(const float* __restrict__ emb,
                                             __half* __restrict__ embh) {
    int stride = gridDim.x * blockDim.x;
    const float2* e2 = (const float2*)emb;
    __half2* h2 = (__half2*)embh;
    for (int i = blockIdx.x * blockDim.x + threadIdx.x; i < N * D / 2; i += stride) {
        float2 v = e2[i];
        h2[i] = __floats2half2_rn(v.x, v.y);
    }
}

// ---------------- Stage 1: xr0 = relu(seg_softmax(edge_vals)-weighted gather) fp16 ----
// One wave (64 lanes) per node; lane owns 2 feature dims (half2).
__global__ __launch_bounds__(256) void k_agg0(const int* __restrict__ rowptr,
                                              const int* __restrict__ sdst,
                                              const float* __restrict__ sval,
                                              const __half* __restrict__ embh,
                                              __half* __restrict__ xr0) {
    int t = threadIdx.x, w = t >> 6, lane = t & 63;
    int node = __builtin_amdgcn_readfirstlane(blockIdx.x * 4 + w);
    int b = rowptr[node], e = rowptr[node + 1];
    const __half2* x2 = (const __half2*)embh;
    float2 acc = {0.f, 0.f};
    float ssum = 0.f;
#pragma unroll 2
    for (int j = b; j < e; ++j) {
        int dn = sdst[j];
        float wgt = __expf(sval[j]);     // max-shift cancels in softmax
        ssum += wgt;
        float2 v = __half22float2(x2[(size_t)dn * 64 + lane]);
        acc.x += wgt * v.x;
        acc.y += wgt * v.y;
    }
    float inv = (e > b) ? 1.f / ssum : 0.f;
    // store relu(x0) in fp16 (all consumers use relu(x))
    ((__half2*)xr0)[(size_t)node * 64 + lane] =
        __floats2half2_rn(fmaxf(acc.x * inv, 0.f), fmaxf(acc.y * inv, 0.f));
}

// ---------------- Per-layer: per-node aS/aN ----------------
// Block = 256 thr = 4 waves = 4 nodes. K (16KB) + attn (1KB) staged in LDS.
__global__ __launch_bounds__(256) void k_prep(const __half* __restrict__ xr,
                                              const float* __restrict__ kern,  // H*DH*DH of this layer
                                              const float* __restrict__ attn,  // H*2*DH of this layer
                                              float* __restrict__ aSN) {
    __shared__ float Ks[H * DH * DH];   // 4096 f32
    __shared__ float As[H * 2 * DH];    // 256 f32
    __shared__ float xs[4][D];
    int t = threadIdx.x;
#pragma unroll
    for (int i = 0; i < 16; ++i) Ks[t + i * 256] = kern[t + i * 256];
    As[t] = attn[t];
    int w = t >> 6, lane = t & 63;
    int node = blockIdx.x * 4 + w;
    if (node < N) {
        float2 xv = __half22float2(((const __half2*)xr)[(size_t)node * 64 + lane]);
        xs[w][2 * lane]     = xv.x;   // already relu'd
        xs[w][2 * lane + 1] = xv.y;
    }
    __syncthreads();
    if (node >= N) return;
    int f = lane & 31;
#pragma unroll
    for (int hh = 0; hh < 2; ++hh) {
        int h = (lane >> 5) + 2 * hh;
        float y = 0.f;
#pragma unroll
        for (int d = 0; d < DH; ++d)
            y += xs[w][h * DH + d] * Ks[(h * DH + d) * DH + f];
        y = fmaxf(y, 0.f);                       // relu(einsum)
        float aS = y * As[h * 2 * DH + f];        // attn first half  (self/src)
        float aN = y * As[h * 2 * DH + DH + f];   // attn second half (neigh/dst)
#pragma unroll
        for (int m = 1; m < 32; m <<= 1) {
            aS += __shfl_xor(aS, m);
            aN += __shfl_xor(aN, m);
        }
        if (f == 0) {
            aSN[(size_t)node * 8 + h]     = aS;
            aSN[(size_t)node * 8 + 4 + h] = aN;
        }
    }
}

// ---------------- Per-layer: global softmax denominator S[h] ----------------
// Edge-parallel grid-stride; hierarchical reduction; ONE atomicAdd/head/block.
__global__ __launch_bounds__(256) void k_edge(const int* __restrict__ edges,
                                              const float* __restrict__ aSN,
                                              float* __restrict__ S) {
    float local[H] = {0.f, 0.f, 0.f, 0.f};
    int stride = gridDim.x * blockDim.x;
    const int2* e2 = (const int2*)edges;
    const float4* a4 = (const float4*)aSN;
    for (int e = blockIdx.x * blockDim.x + threadIdx.x; e < E; e += stride) {
        int2 sd = e2[e];
        float4 vS = a4[(size_t)sd.x * 2];        // aS[src, 0..3]
        float4 vN = a4[(size_t)sd.y * 2 + 1];    // aN[dst, 0..3]
        float a0 = vS.x + vN.x, a1 = vS.y + vN.y, a2 = vS.z + vN.z, a3 = vS.w + vN.w;
        a0 = (a0 >= 0.f) ? a0 : ALPHA * a0;
        a1 = (a1 >= 0.f) ? a1 : ALPHA * a1;
        a2 = (a2 >= 0.f) ? a2 : ALPHA * a2;
        a3 = (a3 >= 0.f) ? a3 : ALPHA * a3;
        local[0] += __expf(a0);
        local[1] += __expf(a1);
        local[2] += __expf(a2);
        local[3] += __expf(a3);
    }
#pragma unroll
    for (int h = 0; h < H; ++h)
#pragma unroll
        for (int m = 1; m < 64; m <<= 1) local[h] += __shfl_xor(local[h], m);
    __shared__ float sm[4][H];
    int lane = threadIdx.x & 63, w = threadIdx.x >> 6;
    if (lane == 0)
#pragma unroll
        for (int h = 0; h < H; ++h) sm[w][h] = local[h];
    __syncthreads();
    if (threadIdx.x < H) {
        float s = sm[0][threadIdx.x] + sm[1][threadIdx.x] +
                  sm[2][threadIdx.x] + sm[3][threadIdx.x];
        atomicAdd(&S[threadIdx.x], s);
    }
}

// ---------------- Per-layer: fused seg-softmax(p) + aggregation + tanh ------------
// Lane owns features 2*lane..2*lane+1 -> head = lane>>4 directly (no shfl).
template <int WRITE_XR>
__global__ __launch_bounds__(256) void k_agg(const int* __restrict__ rowptr,
                                             const int* __restrict__ sdst,
                                             const float* __restrict__ aSN,
                                             const float* __restrict__ S,
                                             const __half* __restrict__ xr,
                                             __half* __restrict__ xr_out,
                                             float* __restrict__ out, int l) {
    int t = threadIdx.x, w = t >> 6, lane = t & 63;
    int node = __builtin_amdgcn_readfirstlane(blockIdx.x * 4 + w);
    int b = rowptr[node], e = rowptr[node + 1];
    int h = lane >> 4;                            // this lane's head
    float aS   = aSN[(size_t)node * 8 + h];
    float invS = 1.f / S[h];
    const __half2* x2 = (const __half2*)xr;
    float2 acc = {0.f, 0.f};
    float ssum = 0.f;
#pragma unroll 2
    for (int j = b; j < e; ++j) {
        int dn = sdst[j];
        float a = aS + aSN[(size_t)dn * 8 + 4 + h];
        a = (a >= 0.f) ? a : ALPHA * a;
        float p = __expf(a) * invS;              // global softmax output
        float wgt = __expf(p);                   // seg softmax numerator (max-shift cancels)
        ssum += wgt;
        float2 v = __half22float2(x2[(size_t)dn * 64 + lane]);  // already relu'd
        acc.x += wgt * v.x;
        acc.y += wgt * v.y;
    }
    float inv = (e > b) ? 1.f / ssum : 0.f;
    float rx = fast_tanh(acc.x * inv);
    float ry = fast_tanh(acc.y * inv);
    // out[node, l*128 + 2*lane .. +1], row stride L*D=256 f32 = 128 float2
    ((float2*)out)[(size_t)node * 128 + l * 64 + lane] = {rx, ry};
    if (WRITE_XR)
        ((__half2*)xr_out)[(size_t)node * 64 + lane] =
            __floats2half2_rn(fmaxf(rx, 0.f), fmaxf(ry, 0.f));
}

// ---------------- launch ----------------
extern "C" void kernel_launch(void* const* d_in, const int* in_sizes, int n_in,
                              void* d_out, int out_size, void* d_ws, size_t ws_size,
                              hipStream_t stream) {
    (void)in_sizes; (void)n_in; (void)out_size; (void)ws_size;
    const float* emb   = (const float*)d_in[0];  // N*D
    const float* evals = (const float*)d_in[1];  // E
    const float* kern  = (const float*)d_in[2];  // L*H*DH*DH
    const float* attn  = (const float*)d_in[3];  // L*H*2*DH
    const int*   edges = (const int*)d_in[4];    // E*2
    float* out = (float*)d_out;

    char* ws = (char*)d_ws;
    size_t off = 0;
    auto take = [&](size_t bytes) -> void* {
        void* p = ws + off;
        off = (off + bytes + 255) & ~(size_t)255;
        return p;
    };
    int*    cnt    = (int*)take((size_t)N * 4);
    int*    rowptr = (int*)take((size_t)(N + 1) * 4);
    int*    head   = (int*)take((size_t)N * 4);
    int*    bsum   = (int*)take((size_t)NB * 4);
    int*    sdst   = (int*)take((size_t)E * 4);
    float*  sval   = (float*)take((size_t)E * 4);
    float*  aSN    = (float*)take((size_t)N * 8 * 4);
    float*  S      = (float*)take(64);           // 2 layers x 4 heads
    __half* embh   = (__half*)take((size_t)N * D * 2);
    __half* xr0    = (__half*)take((size_t)N * D * 2);
    __half* xr1    = (__half*)take((size_t)N * D * 2);

    hipMemsetAsync(cnt, 0, (size_t)N * 4, stream);
    hipMemsetAsync(S, 0, 64, stream);

    int eb = (E + 255) / 256;
    k_count<<<eb, 256, 0, stream>>>(edges, cnt);
    k_scanA<<<NB, SCAN_B, 0, stream>>>(cnt, rowptr, bsum);
    k_scanB<<<1, SCAN_B, 0, stream>>>(bsum);
    k_scanC<<<NB, SCAN_B, 0, stream>>>(rowptr, bsum, head);
    k_scatter<<<eb, 256, 0, stream>>>(edges, evals, head, sdst, sval);
    k_cvt<<<1024, 256, 0, stream>>>(emb, embh);

    int nb = N / 4;   // 4 nodes (waves) per block; N % 4 == 0
    k_agg0<<<nb, 256, 0, stream>>>(rowptr, sdst, sval, embh, xr0);

    // layer 0
    k_prep<<<nb, 256, 0, stream>>>(xr0, kern, attn, aSN);
    k_edge<<<EDGE_BLOCKS, 256, 0, stream>>>(edges, aSN, S);
    k_agg<1><<<nb, 256, 0, stream>>>(rowptr, sdst, aSN, S, xr0, xr1, out, 0);
    // layer 1
    k_prep<<<nb, 256, 0, stream>>>(xr1, kern + (size_t)H * DH * DH,
                                   attn + (size_t)H * 2 * DH, aSN);
    k_edge<<<EDGE_BLOCKS, 256, 0, stream>>>(edges, aSN, S + 4);
    k_agg<0><<<nb, 256, 0, stream>>>(rowptr, sdst, aSN, S + 4, xr1, nullptr, out, 1);
}

// Round 4
// 363.729 us; speedup vs baseline: 5.0163x; 1.1494x over previous
//
#include <hip/hip_runtime.h>
#include <hip/hip_fp16.h>
#include <cmath>

// Problem constants (from reference)
constexpr int N  = 50000;
constexpr int E  = 800000;
constexpr int D  = 128;
constexpr int H  = 4;
constexpr int DH = 32;
constexpr int L  = 2;
constexpr float ALPHA = 0.3f;

constexpr int SCAN_B = 256;
constexpr int NB = (N + SCAN_B - 1) / SCAN_B; // 196 blocks
constexpr int EDGE_BLOCKS = 512;              // k_edge reduction grid

__device__ __forceinline__ float fast_tanh(float x) {
    // tanh(x) = 1 - 2/(exp(2x)+1); exact saturation, err ~1e-6
    return 1.f - 2.f / (__expf(2.f * x) + 1.f);
}

// ---------------- CSR build ----------------

// 2 edges per thread via int4
__global__ void k_count(const int4* __restrict__ e4, int* __restrict__ cnt) {
    int i = blockIdx.x * blockDim.x + threadIdx.x;
    if (i < E / 2) {
        int4 p = e4[i];
        atomicAdd(&cnt[p.x], 1);
        atomicAdd(&cnt[p.z], 1);
    }
}

__global__ void k_scanA(const int* __restrict__ cnt, int* __restrict__ excl,
                        int* __restrict__ bsum) {
    __shared__ int sm[SCAN_B];
    int t = threadIdx.x;
    int i = blockIdx.x * SCAN_B + t;
    int v = (i < N) ? cnt[i] : 0;
    sm[t] = v;
    __syncthreads();
    for (int off = 1; off < SCAN_B; off <<= 1) {
        int add = (t >= off) ? sm[t - off] : 0;
        __syncthreads();
        sm[t] += add;
        __syncthreads();
    }
    if (i < N) excl[i] = sm[t] - v;           // exclusive within block
    if (t == SCAN_B - 1) bsum[blockIdx.x] = sm[t];
}

__global__ void k_scanB(int* __restrict__ bsum) {
    __shared__ int sm[SCAN_B];
    int t = threadIdx.x;
    int v = (t < NB) ? bsum[t] : 0;
    sm[t] = v;
    __syncthreads();
    for (int off = 1; off < SCAN_B; off <<= 1) {
        int add = (t >= off) ? sm[t - off] : 0;
        __syncthreads();
        sm[t] += add;
        __syncthreads();
    }
    if (t < NB) bsum[t] = sm[t] - v;          // exclusive across blocks
}

__global__ void k_scanC(int* __restrict__ rowptr, const int* __restrict__ bsum,
                        int* __restrict__ head) {
    int i = blockIdx.x * SCAN_B + threadIdx.x;
    if (i < N) {
        int r = rowptr[i] + bsum[blockIdx.x];
        rowptr[i] = r;
        head[i]   = r;
    }
    if (i == 0) rowptr[N] = E;
}

// single int2 write per edge: (dst, bitcast(val)) -> 1 cache line alloc, not 2
__global__ void k_scatter(const int* __restrict__ edges, const float* __restrict__ evals,
                          int* __restrict__ head, int2* __restrict__ sde) {
    int e = blockIdx.x * blockDim.x + threadIdx.x;
    if (e < E) {
        int2 sd = ((const int2*)edges)[e];
        int pos = atomicAdd(&head[sd.x], 1);
        sde[pos] = make_int2(sd.y, __float_as_int(evals[e]));
    }
}

// ---------------- emb f32 -> fp16 ----------------
__global__ __launch_bounds__(256) void k_cvt(const float* __restrict__ emb,
                                             __half* __restrict__ embh) {
    int stride = gridDim.x * blockDim.x;
    const float2* e2 = (const float2*)emb;
    __half2* h2 = (__half2*)embh;
    for (int i = blockIdx.x * blockDim.x + threadIdx.x; i < N * D / 2; i += stride) {
        float2 v = e2[i];
        h2[i] = __floats2half2_rn(v.x, v.y);
    }
}

// ---- shared prep tail: wave w computes aS/aN for `node` from relu'd row in xs[w] ----
__device__ __forceinline__ void prep_tail(const float (*xs)[D], const float* Ks,
                                          const float* As, int w, int lane, int node,
                                          float* __restrict__ aSN) {
    int f = lane & 31;
#pragma unroll
    for (int hh = 0; hh < 2; ++hh) {
        int h = (lane >> 5) + 2 * hh;
        float y = 0.f;
#pragma unroll
        for (int d = 0; d < DH; ++d)
            y += xs[w][h * DH + d] * Ks[(h * DH + d) * DH + f];
        y = fmaxf(y, 0.f);                        // relu(einsum)
        float aS = y * As[h * 2 * DH + f];        // attn first half  (self/src)
        float aN = y * As[h * 2 * DH + DH + f];   // attn second half (neigh/dst)
#pragma unroll
        for (int m = 1; m < 32; m <<= 1) {
            aS += __shfl_xor(aS, m);
            aN += __shfl_xor(aN, m);
        }
        if (f == 0) {
            aSN[(size_t)node * 8 + h]     = aS;
            aSN[(size_t)node * 8 + 4 + h] = aN;
        }
    }
}

// ---------------- Stage 1 + fused prep(layer0) ----------------
// One wave per node; lane owns 2 features. Writes xr0 (relu, fp16) and aSN0.
__global__ __launch_bounds__(256) void k_agg0(const int* __restrict__ rowptr,
                                              const int2* __restrict__ sde,
                                              const __half* __restrict__ embh,
                                              __half* __restrict__ xr0,
                                              const float* __restrict__ kern,
                                              const float* __restrict__ attn,
                                              float* __restrict__ aSN) {
    __shared__ float Ks[H * DH * DH];   // 16KB
    __shared__ float As[H * 2 * DH];
    __shared__ float xs[4][D];
    int t = threadIdx.x;
#pragma unroll
    for (int i = 0; i < 16; ++i) Ks[t + i * 256] = kern[t + i * 256];
    As[t] = attn[t];
    __syncthreads();
    int w = t >> 6, lane = t & 63;
    int node = __builtin_amdgcn_readfirstlane(blockIdx.x * 4 + w);
    int b = rowptr[node], e = rowptr[node + 1];
    const __half2* x2 = (const __half2*)embh;
    float2 acc = {0.f, 0.f};
    float ssum = 0.f;
#pragma unroll 4
    for (int j = b; j < e; ++j) {
        int2 dv = sde[j];
        float wgt = __expf(__int_as_float(dv.y));   // max-shift cancels in softmax
        ssum += wgt;
        float2 v = __half22float2(x2[(size_t)dv.x * 64 + lane]);
        acc.x += wgt * v.x;
        acc.y += wgt * v.y;
    }
    float inv = (e > b) ? 1.f / ssum : 0.f;
    float rx = fmaxf(acc.x * inv, 0.f);   // relu(x0)
    float ry = fmaxf(acc.y * inv, 0.f);
    ((__half2*)xr0)[(size_t)node * 64 + lane] = __floats2half2_rn(rx, ry);
    xs[w][2 * lane]     = rx;
    xs[w][2 * lane + 1] = ry;
    __syncthreads();
    prep_tail(xs, Ks, As, w, lane, node, aSN);
}

// ---------------- Per-layer: global softmax denominator S[h] ----------------
// Edge-parallel, 2 edges/thread via int4; ONE atomicAdd/head/block.
__global__ __launch_bounds__(256) void k_edge(const int4* __restrict__ e4,
                                              const float* __restrict__ aSN,
                                              float* __restrict__ S) {
    float local[H] = {0.f, 0.f, 0.f, 0.f};
    int stride = gridDim.x * blockDim.x;
    const float4* a4 = (const float4*)aSN;
    for (int i = blockIdx.x * blockDim.x + threadIdx.x; i < E / 2; i += stride) {
        int4 p = e4[i];
        float4 vS0 = a4[(size_t)p.x * 2];
        float4 vN0 = a4[(size_t)p.y * 2 + 1];
        float4 vS1 = a4[(size_t)p.z * 2];
        float4 vN1 = a4[(size_t)p.w * 2 + 1];
        float a0 = vS0.x + vN0.x, a1 = vS0.y + vN0.y, a2 = vS0.z + vN0.z, a3 = vS0.w + vN0.w;
        float b0 = vS1.x + vN1.x, b1 = vS1.y + vN1.y, b2 = vS1.z + vN1.z, b3 = vS1.w + vN1.w;
        a0 = (a0 >= 0.f) ? a0 : ALPHA * a0;  b0 = (b0 >= 0.f) ? b0 : ALPHA * b0;
        a1 = (a1 >= 0.f) ? a1 : ALPHA * a1;  b1 = (b1 >= 0.f) ? b1 : ALPHA * b1;
        a2 = (a2 >= 0.f) ? a2 : ALPHA * a2;  b2 = (b2 >= 0.f) ? b2 : ALPHA * b2;
        a3 = (a3 >= 0.f) ? a3 : ALPHA * a3;  b3 = (b3 >= 0.f) ? b3 : ALPHA * b3;
        local[0] += __expf(a0) + __expf(b0);
        local[1] += __expf(a1) + __expf(b1);
        local[2] += __expf(a2) + __expf(b2);
        local[3] += __expf(a3) + __expf(b3);
    }
#pragma unroll
    for (int h = 0; h < H; ++h)
#pragma unroll
        for (int m = 1; m < 64; m <<= 1) local[h] += __shfl_xor(local[h], m);
    __shared__ float sm[4][H];
    int lane = threadIdx.x & 63, w = threadIdx.x >> 6;
    if (lane == 0)
#pragma unroll
        for (int h = 0; h < H; ++h) sm[w][h] = local[h];
    __syncthreads();
    if (threadIdx.x < H) {
        float s = sm[0][threadIdx.x] + sm[1][threadIdx.x] +
                  sm[2][threadIdx.x] + sm[3][threadIdx.x];
        atomicAdd(&S[threadIdx.x], s);
    }
}

// ---------------- Layer 0 aggregation + fused prep(layer1) ----------------
// Reads aSN0/S0/xr0, writes out(l=0), xr1 (relu fp16), aSN1. aSN buffers MUST differ
// (random reads of other nodes' aSN0 race with writes otherwise).
__global__ __launch_bounds__(256) void k_agg_fused(const int* __restrict__ rowptr,
                                                   const int2* __restrict__ sde,
                                                   const float* __restrict__ aSN_in,
                                                   const float* __restrict__ S,
                                                   const __half* __restrict__ xr,
                                                   __half* __restrict__ xr_out,
                                                   float* __restrict__ out,
                                                   const float* __restrict__ kern,
                                                   const float* __restrict__ attn,
                                                   float* __restrict__ aSN_out) {
    __shared__ float Ks[H * DH * DH];
    __shared__ float As[H * 2 * DH];
    __shared__ float xs[4][D];
    int t = threadIdx.x;
#pragma unroll
    for (int i = 0; i < 16; ++i) Ks[t + i * 256] = kern[t + i * 256];
    As[t] = attn[t];
    __syncthreads();
    int w = t >> 6, lane = t & 63;
    int node = __builtin_amdgcn_readfirstlane(blockIdx.x * 4 + w);
    int b = rowptr[node], e = rowptr[node + 1];
    int h = lane >> 4;
    float aS   = aSN_in[(size_t)node * 8 + h];
    float invS = 1.f / S[h];
    const __half2* x2 = (const __half2*)xr;
    float2 acc = {0.f, 0.f};
    float ssum = 0.f;
#pragma unroll 4
    for (int j = b; j < e; ++j) {
        int2 dv = sde[j];
        int dn = dv.x;
        float a = aS + aSN_in[(size_t)dn * 8 + 4 + h];
        a = (a >= 0.f) ? a : ALPHA * a;
        float p = __expf(a) * invS;              // global softmax output
        float wgt = __expf(p);                   // seg softmax numerator
        ssum += wgt;
        float2 v = __half22float2(x2[(size_t)dn * 64 + lane]);  // already relu'd
        acc.x += wgt * v.x;
        acc.y += wgt * v.y;
    }
    float inv = (e > b) ? 1.f / ssum : 0.f;
    float rx = fast_tanh(acc.x * inv);
    float ry = fast_tanh(acc.y * inv);
    ((float2*)out)[(size_t)node * 128 + lane] = {rx, ry};   // l = 0
    float qx = fmaxf(rx, 0.f), qy = fmaxf(ry, 0.f);
    ((__half2*)xr_out)[(size_t)node * 64 + lane] = __floats2half2_rn(qx, qy);
    xs[w][2 * lane]     = qx;
    xs[w][2 * lane + 1] = qy;
    __syncthreads();
    prep_tail(xs, Ks, As, w, lane, node, aSN_out);
}

// ---------------- Layer 1 aggregation (last; no prep) ----------------
__global__ __launch_bounds__(256) void k_agg_last(const int* __restrict__ rowptr,
                                                  const int2* __restrict__ sde,
                                                  const float* __restrict__ aSN_in,
                                                  const float* __restrict__ S,
                                                  const __half* __restrict__ xr,
                                                  float* __restrict__ out) {
    int t = threadIdx.x, w = t >> 6, lane = t & 63;
    int node = __builtin_amdgcn_readfirstlane(blockIdx.x * 4 + w);
    int b = rowptr[node], e = rowptr[node + 1];
    int h = lane >> 4;
    float aS   = aSN_in[(size_t)node * 8 + h];
    float invS = 1.f / S[h];
    const __half2* x2 = (const __half2*)xr;
    float2 acc = {0.f, 0.f};
    float ssum = 0.f;
#pragma unroll 4
    for (int j = b; j < e; ++j) {
        int2 dv = sde[j];
        int dn = dv.x;
        float a = aS + aSN_in[(size_t)dn * 8 + 4 + h];
        a = (a >= 0.f) ? a : ALPHA * a;
        float p = __expf(a) * invS;
        float wgt = __expf(p);
        ssum += wgt;
        float2 v = __half22float2(x2[(size_t)dn * 64 + lane]);
        acc.x += wgt * v.x;
        acc.y += wgt * v.y;
    }
    float inv = (e > b) ? 1.f / ssum : 0.f;
    float rx = fast_tanh(acc.x * inv);
    float ry = fast_tanh(acc.y * inv);
    ((float2*)out)[(size_t)node * 128 + 64 + lane] = {rx, ry};  // l = 1
}

// ---------------- launch ----------------
extern "C" void kernel_launch(void* const* d_in, const int* in_sizes, int n_in,
                              void* d_out, int out_size, void* d_ws, size_t ws_size,
                              hipStream_t stream) {
    (void)in_sizes; (void)n_in; (void)out_size; (void)ws_size;
    const float* emb   = (const float*)d_in[0];  // N*D
    const float* evals = (const float*)d_in[1];  // E
    const float* kern  = (const float*)d_in[2];  // L*H*DH*DH
    const float* attn  = (const float*)d_in[3];  // L*H*2*DH
    const int*   edges = (const int*)d_in[4];    // E*2
    float* out = (float*)d_out;

    char* ws = (char*)d_ws;
    size_t off = 0;
    auto take = [&](size_t bytes) -> void* {
        void* p = ws + off;
        off = (off + bytes + 255) & ~(size_t)255;
        return p;
    };
    int*    cnt    = (int*)take((size_t)N * 4);
    int*    rowptr = (int*)take((size_t)(N + 1) * 4);
    int*    head   = (int*)take((size_t)N * 4);
    int*    bsum   = (int*)take((size_t)NB * 4);
    int2*   sde    = (int2*)take((size_t)E * 8);
    float*  aSN0   = (float*)take((size_t)N * 8 * 4);
    float*  aSN1   = (float*)take((size_t)N * 8 * 4);
    float*  S      = (float*)take(64);           // 2 layers x 4 heads
    __half* embh   = (__half*)take((size_t)N * D * 2);
    __half* xr0    = (__half*)take((size_t)N * D * 2);
    __half* xr1    = (__half*)take((size_t)N * D * 2);

    hipMemsetAsync(cnt, 0, (size_t)N * 4, stream);
    hipMemsetAsync(S, 0, 64, stream);

    k_count<<<(E / 2 + 255) / 256, 256, 0, stream>>>((const int4*)edges, cnt);
    k_scanA<<<NB, SCAN_B, 0, stream>>>(cnt, rowptr, bsum);
    k_scanB<<<1, SCAN_B, 0, stream>>>(bsum);
    k_scanC<<<NB, SCAN_B, 0, stream>>>(rowptr, bsum, head);
    k_scatter<<<(E + 255) / 256, 256, 0, stream>>>(edges, evals, head, sde);
    k_cvt<<<1024, 256, 0, stream>>>(emb, embh);

    int nb = N / 4;   // 4 nodes (waves) per block; N % 4 == 0
    k_agg0<<<nb, 256, 0, stream>>>(rowptr, sde, embh, xr0, kern, attn, aSN0);
    k_edge<<<EDGE_BLOCKS, 256, 0, stream>>>((const int4*)edges, aSN0, S);
    k_agg_fused<<<nb, 256, 0, stream>>>(rowptr, sde, aSN0, S, xr0, xr1, out,
                                        kern + (size_t)H * DH * DH,
                                        attn + (size_t)H * 2 * DH, aSN1);
    k_edge<<<EDGE_BLOCKS, 256, 0, stream>>>((const int4*)edges, aSN1, S + 4);
    k_agg_last<<<nb, 256, 0, stream>>>(rowptr, sde, aSN1, S + 4, xr1, out);
}